// Round 5
// baseline (552.908 us; speedup 1.0000x reference)
//
#include <hip/hip_runtime.h>
#include <hip/hip_bf16.h>

#define B_ 2
#define C_ 16
#define H_ 384
#define W_ 1280
#define HT_ 96
#define WT_ 320
#define SP_ (HT_*WT_)      /* 30720 */
#define NPIX_ (B_*SP_)     /* 61440 */
#define HP_ 48
#define WP_ 160
#define SPP_ (HP_*WP_)     /* 7680: prev spatial */

__device__ __forceinline__ float leaky(float v){ return v >= 0.f ? v : 0.2f*v; }

// ---------------- sentinel (ws too small): encode ws_size into the output ----------------
__global__ __launch_bounds__(256) void k_sentinel(float* __restrict__ out, int n, float v){
    int i = blockIdx.x*256 + threadIdx.x;
    if (i < n) out[i] = v;
}

// ================= fused front: warp(cur)+warp(prev)+dec(x2)+conv0 =================
// block = 16 tile px in one tile row (64 full-res x, 4 full-res y), 256 threads.
// Phase 1: thread = one full-res px (wave = 64 consecutive x in ONE row -> coalesced).
//   computes fsum + 3 cur-costs + 3 prev-costs -> LDS.
// Phase 2: dec 1x1 conv (64->16) for cur & prev, -> LDS.
// Phase 3: conv0 1x1 (64->32) -> h. cv volumes never touch global memory.
__global__ __launch_bounds__(256) void k_front(
        const float* __restrict__ cur, const float* __restrict__ prev,
        const float* __restrict__ fl, const float* __restrict__ fr,
        const float* __restrict__ wdec, const float* __restrict__ bdec,
        const float* __restrict__ w0, const float* __restrict__ b0,
        float* __restrict__ h){
    __shared__ float wdl[64][17];    // wdec [ic][oc], pad
    __shared__ float w0l[64][33];    // w0   [ic][oc], pad
    __shared__ float pl6[16][6];     // per tile px: curD,curDx,curDy, upD,prevDx,prevDy
    __shared__ float vals[16][117];  // [px][ch]: 0..15 fsum, 16..63 cur s(-1,0,1), 64..111 prev
    __shared__ float cvl[16][33];    // [px][0..15 ccv | 16..31 pcv]
    __shared__ float cul[16][33];    // [px][0..15 cur | 16..31 up_prev]
    int tid = threadIdx.x;
    int ty = blockIdx.y, b = blockIdx.z;
    int tx0 = blockIdx.x*16;

    for (int i = tid; i < 1024; i += 256) wdl[i>>4][i&15] = wdec[(i&15)*64 + (i>>4)];
    for (int i = tid; i < 2048; i += 256) w0l[i>>5][i&31] = w0[(i&31)*64 + (i>>5)];
    if (tid < 16){
        int tx = tx0 + tid;
        size_t pb = ((size_t)(b*16)*HT_ + ty)*WT_ + tx;
        pl6[tid][0] = cur[pb];
        pl6[tid][1] = cur[pb + SP_];
        pl6[tid][2] = cur[pb + 2*SP_];
        size_t qb = ((size_t)(b*16)*HP_ + (ty>>1))*WP_ + (tx>>1);
        float pd  = prev[qb];
        float pdx = prev[qb + SPP_];
        float pdy = prev[qb + 2*SPP_];
        float cx = (tx & 1) ? 0.5f : -0.5f;
        float cy = (ty & 1) ? 0.5f : -0.5f;
        pl6[tid][3] = (pd + cx*pdx + cy*pdy) * 2.0f;
        pl6[tid][4] = pdx;
        pl6[tid][5] = pdy;
    }
    // stage cur/up for conv0 (independent of vals)
    {
        int i = tid >> 4, px = tid & 15;          // i = channel, px = tile px
        int tx = tx0 + px;
        cul[px][i] = cur[(size_t)(b*16 + i)*SP_ + (size_t)ty*WT_ + tx];
        float upv;
        if (i == 0) upv = 0.f;  // filled after sync from pl6 (needs pl6)
        else upv = prev[(size_t)(b*16 + i)*SPP_ + (size_t)(ty>>1)*WP_ + (tx>>1)];
        cul[px][16 + i] = upv;
    }
    __syncthreads();
    if (tid < 16) cul[tid][16] = pl6[tid][3];    // up_prev ch0 = upsampled d-plane

    int r  = tid >> 6;            // 0..3  full-res row within tile row
    int cx = tid & 63;            // 0..63 full-res x within strip
    int tp = cx >> 2, xx = cx & 3, yy = r;
    int x = tx0*4 + cx, y = ty*4 + r;
    int sub = yy*4 + xx;

    float dC = pl6[tp][0], dxC = pl6[tp][1], dyC = pl6[tp][2];
    float dP = pl6[tp][3], dxP = pl6[tp][4], dyP = pl6[tp][5];
    const float c4[4] = {-1.5f,-0.5f,0.5f,1.5f};
    float ldC = dC + c4[xx]*dxC + c4[yy]*dyC;
    float ldP = dP + c4[xx]*dxP + c4[yy]*dyP;

    float wloC[4], whiC[4], wloP[4], whiP[4];
    int xcC[4], xcP[4];
    {
        float ix  = (float)x - ldC;
        float x0f = floorf(ix);
        float wx  = ix - x0f;
        int x0 = (int)x0f;
        #pragma unroll
        for (int j = 0; j < 4; j++){
            int xi = x0 + (j-1);
            bool ok = (xi >= 0) && (xi < W_);
            xcC[j]  = xi < 0 ? 0 : (xi > W_-1 ? W_-1 : xi);
            wloC[j] = ok ? (1.f - wx) : 0.f;
            whiC[j] = ok ? wx : 0.f;
        }
        ix  = (float)x - ldP;
        x0f = floorf(ix);
        wx  = ix - x0f;
        x0 = (int)x0f;
        #pragma unroll
        for (int j = 0; j < 4; j++){
            int xi = x0 + (j-1);
            bool ok = (xi >= 0) && (xi < W_);
            xcP[j]  = xi < 0 ? 0 : (xi > W_-1 ? W_-1 : xi);
            wloP[j] = ok ? (1.f - wx) : 0.f;
            whiP[j] = ok ? wx : 0.f;
        }
    }
    const float* pl = fl + (size_t)(b*C_)*H_*W_ + (size_t)y*W_ + x;
    const float* pr = fr + (size_t)(b*C_)*H_*W_ + (size_t)y*W_;
    float fsum=0.f, c0=0.f, c1=0.f, c2=0.f, p0=0.f, p1=0.f, p2=0.f;
    #pragma unroll 8
    for (int c = 0; c < C_; c++){
        float a = pl[(size_t)c*H_*W_];
        const float* prc = pr + (size_t)c*H_*W_;
        float uC0 = prc[xcC[0]], uC1 = prc[xcC[1]], uC2 = prc[xcC[2]], uC3 = prc[xcC[3]];
        float uP0 = prc[xcP[0]], uP1 = prc[xcP[1]], uP2 = prc[xcP[2]], uP3 = prc[xcP[3]];
        fsum += fabsf(a);
        c0 += fabsf(a - (wloC[2]*uC2 + whiC[3]*uC3));
        c1 += fabsf(a - (wloC[1]*uC1 + whiC[2]*uC2));
        c2 += fabsf(a - (wloC[0]*uC0 + whiC[1]*uC1));
        p0 += fabsf(a - (wloP[2]*uP2 + whiP[3]*uP3));
        p1 += fabsf(a - (wloP[1]*uP1 + whiP[2]*uP2));
        p2 += fabsf(a - (wloP[0]*uP0 + whiP[1]*uP1));
    }
    vals[tp][sub]      = fsum;
    vals[tp][16+sub]   = c0;
    vals[tp][32+sub]   = c1;
    vals[tp][48+sub]   = c2;
    vals[tp][64+sub]   = p0;
    vals[tp][80+sub]   = p1;
    vals[tp][96+sub]   = p2;
    __syncthreads();

    // dec conv: 256 thr = 16 oc x 16 px
    {
        int oc = tid >> 4, px = tid & 15;
        float bb = bdec[oc];
        float accC = bb, accP = bb;
        #pragma unroll 8
        for (int ic = 0; ic < 16; ic++){
            float wv = wdl[ic][oc];
            accC += vals[px][ic] * wv;
            accP += vals[px][ic] * wv;
        }
        #pragma unroll 8
        for (int ic = 16; ic < 64; ic++){
            float wv = wdl[ic][oc];
            accC += vals[px][ic]      * wv;
            accP += vals[px][ic + 48] * wv;
        }
        cvl[px][oc]      = leaky(accC);
        cvl[px][16 + oc] = leaky(accP);
    }
    __syncthreads();

    // conv0: 256 thr = 16 oc-pairs x 16 px
    {
        int pair = tid >> 4, px = tid & 15;
        int oc0 = pair*2;
        float a0 = b0[oc0], a1 = b0[oc0+1];
        #pragma unroll 4
        for (int i = 0; i < 16; i++){
            float v = cul[px][i];
            a0 += v*w0l[i][oc0]; a1 += v*w0l[i][oc0+1];
        }
        #pragma unroll 4
        for (int i = 0; i < 16; i++){
            float v = cvl[px][i];
            a0 += v*w0l[16+i][oc0]; a1 += v*w0l[16+i][oc0+1];
        }
        #pragma unroll 4
        for (int i = 0; i < 16; i++){
            float v = cul[px][16+i];
            a0 += v*w0l[32+i][oc0]; a1 += v*w0l[32+i][oc0+1];
        }
        #pragma unroll 4
        for (int i = 0; i < 16; i++){
            float v = cvl[px][16+i];
            a0 += v*w0l[48+i][oc0]; a1 += v*w0l[48+i][oc0+1];
        }
        size_t ob = (size_t)(b*32 + oc0)*SP_ + (size_t)ty*WT_ + tx0 + px;
        h[ob]       = leaky(a0);
        h[ob + SP_] = leaky(a1);
    }
}

// ---------------- conv3x3 32->32, pad1, leaky, optional residual ----------------
// tile 32x4 px, 256 thr: thread = 4 oc x 4 px; ic chunked by 8.
// it rows padded to 36 for aligned float4 window reads.
// NOTE: when RES, res and out may ALIAS (in-place h update); element-wise safe.
template<bool RES>
__global__ __launch_bounds__(256) void k_conv3(const float* __restrict__ in,
        const float* __restrict__ w, const float* __restrict__ bias,
        const float* res, float* out){
    __shared__ float it[8][6][36];
    __shared__ float wl[8][9][32];
    int tid = threadIdx.x;
    int gx = blockIdx.x*32, gy = blockIdx.y*4;
    int b = blockIdx.z;
    int ocg  = tid >> 5;          // 0..7  -> 4 oc each
    int slot = tid & 31;
    int tx4  = (slot & 7)*4;      // 0,4,...,28
    int ty   = slot >> 3;         // 0..3
    float acc[4][4];
    #pragma unroll
    for (int o = 0; o < 4; o++)
        #pragma unroll
        for (int p = 0; p < 4; p++) acc[o][p] = 0.f;

    for (int ic0 = 0; ic0 < 32; ic0 += 8){
        for (int i = tid; i < 8*6*34; i += 256){
            int ic = i/(6*34); int rr = i - ic*(6*34);
            int iy = rr/34;    int ixx = rr - iy*34;
            int ggy = gy + iy - 1, ggx = gx + ixx - 1;
            float v = 0.f;
            if (ggy >= 0 && ggy < HT_ && ggx >= 0 && ggx < WT_)
                v = in[((size_t)(b*32 + ic0+ic)*HT_ + ggy)*WT_ + ggx];
            it[ic][iy][ixx] = v;
        }
        for (int i = tid; i < 2304; i += 256){
            int ic = i/288; int rr = i - ic*288;
            int kk = rr >> 5; int oc = rr & 31;
            wl[ic][kk][oc] = w[(size_t)(oc*32 + ic0+ic)*9 + kk];
        }
        __syncthreads();
        #pragma unroll
        for (int ic = 0; ic < 8; ic++){
            #pragma unroll
            for (int dy = 0; dy < 3; dy++){
                const float4 va = *(const float4*)(&it[ic][ty+dy][tx4]);
                const float2 vb = *(const float2*)(&it[ic][ty+dy][tx4+4]);
                const float inr[6] = {va.x, va.y, va.z, va.w, vb.x, vb.y};
                #pragma unroll
                for (int dx = 0; dx < 3; dx++){
                    const float4 wv = *(const float4*)(&wl[ic][dy*3+dx][ocg*4]);
                    const float wa[4] = {wv.x, wv.y, wv.z, wv.w};
                    #pragma unroll
                    for (int o = 0; o < 4; o++)
                        #pragma unroll
                        for (int p = 0; p < 4; p++)
                            acc[o][p] += inr[dx+p]*wa[o];
                }
            }
        }
        __syncthreads();
    }
    int oc0 = ocg*4;
    int yo = gy + ty;
    #pragma unroll
    for (int o = 0; o < 4; o++){
        float bo = bias[oc0+o];
        size_t ob = ((size_t)(b*32 + oc0+o)*HT_ + yo)*WT_ + gx + tx4;
        #pragma unroll
        for (int p = 0; p < 4; p++){
            float v = acc[o][p] + bo;
            if (RES) v += res[ob+p];
            out[ob+p] = leaky(v);
        }
    }
}

// ---------------- last conv3x3 32->34 + epilogue, conv3-style blocking ----------------
// tile 32x4 px; ocg 0..7 -> oc 4 each (0..31); wave 0 (ocg 0,1) also computes oc 32,33.
// conv result exchanged through LDS uu[34][128], epilogue by 128 threads.
__global__ __launch_bounds__(256) void k_last(const float* __restrict__ in,
        const float* __restrict__ w, const float* __restrict__ bias,
        const float* __restrict__ cur, const float* __restrict__ prev,
        float* __restrict__ out){
    __shared__ float it[8][6][36];
    __shared__ float wl[8][9][36];
    __shared__ float uu[34][129];
    int tid = threadIdx.x;
    int gx = blockIdx.x*32, gy = blockIdx.y*4;
    int b = blockIdx.z;
    int ocg  = tid >> 5;
    int slot = tid & 31;
    int tx4  = (slot & 7)*4;
    int ty   = slot >> 3;
    float acc[4][4];
    float acce[4];                 // extra oc = 32+ocg for ocg<2
    #pragma unroll
    for (int o = 0; o < 4; o++){
        acce[o] = 0.f;
        #pragma unroll
        for (int p = 0; p < 4; p++) acc[o][p] = 0.f;
    }

    for (int ic0 = 0; ic0 < 32; ic0 += 8){
        for (int i = tid; i < 8*6*34; i += 256){
            int ic = i/(6*34); int rr = i - ic*(6*34);
            int iy = rr/34;    int ixx = rr - iy*34;
            int ggy = gy + iy - 1, ggx = gx + ixx - 1;
            float v = 0.f;
            if (ggy >= 0 && ggy < HT_ && ggx >= 0 && ggx < WT_)
                v = in[((size_t)(b*32 + ic0+ic)*HT_ + ggy)*WT_ + ggx];
            it[ic][iy][ixx] = v;
        }
        for (int i = tid; i < 8*9*34; i += 256){
            int ic = i/306; int rr = i - ic*306;
            int kk = rr/34; int oc = rr - kk*34;
            wl[ic][kk][oc] = w[(size_t)(oc*32 + ic0+ic)*9 + kk];
        }
        __syncthreads();
        #pragma unroll
        for (int ic = 0; ic < 8; ic++){
            #pragma unroll
            for (int dy = 0; dy < 3; dy++){
                const float4 va = *(const float4*)(&it[ic][ty+dy][tx4]);
                const float2 vb = *(const float2*)(&it[ic][ty+dy][tx4+4]);
                const float inr[6] = {va.x, va.y, va.z, va.w, vb.x, vb.y};
                #pragma unroll
                for (int dx = 0; dx < 3; dx++){
                    const float4 wv = *(const float4*)(&wl[ic][dy*3+dx][ocg*4]);
                    const float wa[4] = {wv.x, wv.y, wv.z, wv.w};
                    #pragma unroll
                    for (int o = 0; o < 4; o++)
                        #pragma unroll
                        for (int p = 0; p < 4; p++)
                            acc[o][p] += inr[dx+p]*wa[o];
                    if (ocg < 2){
                        float we = wl[ic][dy*3+dx][32+ocg];
                        #pragma unroll
                        for (int p = 0; p < 4; p++)
                            acce[p] += inr[dx+p]*we;
                    }
                }
            }
        }
        __syncthreads();
    }
    // deposit u = conv + bias into LDS
    {
        int oc0 = ocg*4;
        int pxb = ty*32 + tx4;
        #pragma unroll
        for (int o = 0; o < 4; o++){
            float bo = bias[oc0+o];
            #pragma unroll
            for (int p = 0; p < 4; p++)
                uu[oc0+o][pxb+p] = acc[o][p] + bo;
        }
        if (ocg < 2){
            float bo = bias[32+ocg];
            #pragma unroll
            for (int p = 0; p < 4; p++)
                uu[32+ocg][pxb+p] = acce[p] + bo;
        }
    }
    __syncthreads();
    // epilogue: 128 px by threads 0..127
    if (tid < 128){
        int px = tid;
        int x = gx + (px & 31);
        int y = gy + (px >> 5);
        size_t pix = (size_t)y*WT_ + x;
        float conf0 = uu[0][px];
        float conf1 = uu[1][px];
        bool m = conf1 > conf0;
        size_t src = ((size_t)(b*16)*HP_ + (y>>1))*WP_ + (x>>1);
        float cx = (x & 1) ? 0.5f : -0.5f;
        float cy = (y & 1) ? 0.5f : -0.5f;
        const float* cp = cur + (size_t)b*16*SP_ + pix;
        float* o0 = out +               (size_t)b*16*SP_ + pix;
        float* o1 = out +  983040u  +   (size_t)b*17*SP_ + pix;
        float* o2 = out + 2027520u  +   (size_t)b*17*SP_ + pix;
        #pragma unroll
        for (int c = 0; c < 16; c++){
            float upv;
            if (c == 0){
                float dv  = prev[src];
                float dxv = prev[src + SPP_];
                float dyv = prev[src + 2*SPP_];
                upv = (dv + cx*dxv + cy*dyv) * 2.0f;
            } else {
                upv = prev[src + (size_t)c*SPP_];
            }
            float ucv = cp[(size_t)c*SP_] + uu[18+c][px];
            upv = upv + uu[2+c][px];
            if (c == 0){ ucv = fmaxf(ucv, 0.f); upv = fmaxf(upv, 0.f); }
            float rf = m ? ucv : upv;
            o0[(size_t)c*SP_] = rf;
            o1[(size_t)c*SP_] = ucv;
            o2[(size_t)c*SP_] = upv;
        }
        o1[(size_t)16*SP_] = conf1;
        o2[(size_t)16*SP_] = conf0;
    }
}

#define WS_NEED (32u*NPIX_*4u)   /* h: (B,32,96,320) f32 = 7,864,320 B */
#define OUT_ELEMS 3072000

extern "C" void kernel_launch(void* const* d_in, const int* in_sizes, int n_in,
                              void* d_out, int out_size, void* d_ws, size_t ws_size,
                              hipStream_t stream) {
    const float* fea_l  = (const float*)d_in[0];
    const float* fea_r  = (const float*)d_in[1];
    const float* cur    = (const float*)d_in[2];
    const float* prev   = (const float*)d_in[3];
    const float* w_dec  = (const float*)d_in[4];
    const float* b_dec  = (const float*)d_in[5];
    const float* w0     = (const float*)d_in[6];
    const float* b0     = (const float*)d_in[7];
    const float* w_r0c1 = (const float*)d_in[8];
    const float* b_r0c1 = (const float*)d_in[9];
    const float* w_r0c2 = (const float*)d_in[10];
    const float* b_r0c2 = (const float*)d_in[11];
    const float* w_r1c1 = (const float*)d_in[12];
    const float* b_r1c1 = (const float*)d_in[13];
    const float* w_r1c2 = (const float*)d_in[14];
    const float* b_r1c2 = (const float*)d_in[15];
    const float* w_last = (const float*)d_in[16];
    const float* b_last = (const float*)d_in[17];

    float* out = (float*)d_out;

    if (ws_size < (size_t)WS_NEED){
        k_sentinel<<<(OUT_ELEMS+255)/256, 256, 0, stream>>>(out, OUT_ELEMS, (float)(ws_size >> 10));
        return;
    }

    float* h = (float*)d_ws;          // (B,32,96,320) f32, 7.86 MB
    float* t = out;                   // 1,966,080 floats staged in d_out (dead before k_last)

    dim3 gf(20, 96, 2);
    k_front<<<gf, 256, 0, stream>>>(cur, prev, fea_l, fea_r, w_dec, b_dec, w0, b0, h);

    dim3 g3(10, 24, 2);
    k_conv3<false><<<g3, 256, 0, stream>>>(h, w_r0c1, b_r0c1, nullptr, t);
    k_conv3<true> <<<g3, 256, 0, stream>>>(t, w_r0c2, b_r0c2, h, h);     // in-place residual
    k_conv3<false><<<g3, 256, 0, stream>>>(h, w_r1c1, b_r1c1, nullptr, t);
    k_conv3<true> <<<g3, 256, 0, stream>>>(t, w_r1c2, b_r1c2, h, h);     // in-place residual

    dim3 gl(10, 24, 2);
    k_last<<<gl, 256, 0, stream>>>(h, w_last, b_last, cur, prev, out);
}